// Round 1
// baseline (372.319 us; speedup 1.0000x reference)
//
#include <hip/hip_runtime.h>
#include <hip/hip_bf16.h>
#include <math.h>

typedef __bf16 bf16;
typedef __bf16 bf16x8 __attribute__((ext_vector_type(8)));
typedef __bf16 bf16x4 __attribute__((ext_vector_type(4)));
typedef float f32x4 __attribute__((ext_vector_type(4)));

#define T_SEQ 1024
#define NH 16
#define HD 64
#define DM 1024

__device__ __forceinline__ f32x4 mfma16(bf16x8 a, bf16x8 b, f32x4 c) {
  return __builtin_amdgcn_mfma_f32_16x16x32_bf16(a, b, c, 0, 0, 0);
}

// ---------------- bias table: table[d][h], d = i-j in [0,1023] ----------------
// heads 0..7: sum_{t<32} cos(d*f)+sin(d*f), f = 10000^-((h*32+t)/512)
// heads 8..15: constant = sum_{t<32} (pi[(h-8)*32+t][0] + pi[...][1])
__global__ void hope_bias_kernel(const float* __restrict__ pi, float* __restrict__ table) {
  int idx = blockIdx.x * blockDim.x + threadIdx.x;  // 0..16383
  if (idx >= 1024 * NH) return;
  int d = idx >> 4, h = idx & 15;
  float s = 0.f;
  if (h < 8) {
    int p0 = h * 32;
    for (int t = 0; t < 32; ++t) {
      double fr = pow(10000.0, -((double)(p0 + t)) / 512.0);
      float f = (float)fr;
      float theta = (float)d * f;
      s += cosf(theta) + sinf(theta);
    }
  } else {
    int p0 = (h - 8) * 32;
    for (int t = 0; t < 32; ++t)
      s += pi[(p0 + t) * 2] + pi[(p0 + t) * 2 + 1];
  }
  table[d * NH + h] = s;
}

// ---------------- f32 -> bf16 convert (vectorized) ----------------
__global__ void cvt_kernel(const float* __restrict__ in, bf16* __restrict__ out, int n) {
  int i = (blockIdx.x * blockDim.x + threadIdx.x) * 4;
  if (i < n) {
    float4 v = *reinterpret_cast<const float4*>(in + i);
    bf16x4 o;
    o[0] = (bf16)v.x; o[1] = (bf16)v.y; o[2] = (bf16)v.z; o[3] = (bf16)v.w;
    *reinterpret_cast<bf16x4*>(out + i) = o;
  }
}

// ---------------- shared GEMM mainloop: C[m,n] = sum_k A[m,k]*Bt[n,k] ----------------
// 128x128 tile, BK=64, 4 waves each computing a 64x64 sub-tile (4x4 MFMA frags)
__device__ __forceinline__ void gemm_tile(
    const bf16* __restrict__ A, const bf16* __restrict__ Bt,
    int Kdim, int lda, int ldb, int m0, int n0,
    bf16 (*As)[72], bf16 (*Bs)[72],
    f32x4 acc[4][4], int tid)
{
  const int lane = tid & 63;
  const int wave = tid >> 6;
  const int wmv = (wave >> 1) * 64;
  const int wnv = (wave & 1) * 64;
  const int g = lane >> 4, lr = lane & 15;
  const int srow = tid >> 3, scol = (tid & 7) * 8;

  for (int k0 = 0; k0 < Kdim; k0 += 64) {
#pragma unroll
    for (int i = 0; i < 4; ++i)
      *reinterpret_cast<bf16x8*>(&As[srow + 32 * i][scol]) =
          *reinterpret_cast<const bf16x8*>(&A[(size_t)(m0 + srow + 32 * i) * lda + k0 + scol]);
#pragma unroll
    for (int i = 0; i < 4; ++i)
      *reinterpret_cast<bf16x8*>(&Bs[srow + 32 * i][scol]) =
          *reinterpret_cast<const bf16x8*>(&Bt[(size_t)(n0 + srow + 32 * i) * ldb + k0 + scol]);
    __syncthreads();
#pragma unroll
    for (int kk = 0; kk < 2; ++kk) {
      bf16x8 aF[4], bF[4];
#pragma unroll
      for (int mi = 0; mi < 4; ++mi)
        aF[mi] = *reinterpret_cast<const bf16x8*>(&As[wmv + mi * 16 + lr][kk * 32 + g * 8]);
#pragma unroll
      for (int ni = 0; ni < 4; ++ni)
        bF[ni] = *reinterpret_cast<const bf16x8*>(&Bs[wnv + ni * 16 + lr][kk * 32 + g * 8]);
#pragma unroll
      for (int mi = 0; mi < 4; ++mi)
#pragma unroll
        for (int ni = 0; ni < 4; ++ni)
          acc[mi][ni] = mfma16(aF[mi], bF[ni], acc[mi][ni]);
    }
    __syncthreads();
  }
}

// ---------------- QKV projection: qkv[m,n] -> Q/K/Vt (bf16) ----------------
__global__ __launch_bounds__(256) void gemm_qkv_kernel(
    const bf16* __restrict__ xb, const bf16* __restrict__ wb,
    const float* __restrict__ bias,
    bf16* __restrict__ Q, bf16* __restrict__ K, bf16* __restrict__ Vt)
{
  __shared__ bf16 As[128][72];
  __shared__ bf16 Bs[128][72];
  f32x4 acc[4][4];
  f32x4 z = {0.f, 0.f, 0.f, 0.f};
#pragma unroll
  for (int i = 0; i < 4; ++i)
#pragma unroll
    for (int j = 0; j < 4; ++j) acc[i][j] = z;
  const int m0 = blockIdx.y * 128, n0 = blockIdx.x * 128;
  gemm_tile(xb, wb, DM, DM, DM, m0, n0, As, Bs, acc, threadIdx.x);

  const int lane = threadIdx.x & 63, wave = threadIdx.x >> 6;
  const int wmv = (wave >> 1) * 64, wnv = (wave & 1) * 64;
  const int g = lane >> 4, lr = lane & 15;
#pragma unroll
  for (int mi = 0; mi < 4; ++mi) {
#pragma unroll
    for (int ni = 0; ni < 4; ++ni) {
      int col = n0 + wnv + ni * 16 + lr;
      int c3 = col >> 10, rem = col & 1023;
      int hh = rem >> 6, dd = rem & 63;
      float bv = bias[col];
#pragma unroll
      for (int r = 0; r < 4; ++r) {
        int row = m0 + wmv + mi * 16 + g * 4 + r;
        int bb = row >> 10, t = row & 1023;
        float v = acc[mi][ni][r] + bv;
        size_t bhh = (size_t)(bb * NH + hh);
        bf16 o = (bf16)v;
        if (c3 == 0)      Q[(bhh * T_SEQ + t) * HD + dd] = o;
        else if (c3 == 1) K[(bhh * T_SEQ + t) * HD + dd] = o;
        else              Vt[(bhh * HD + dd) * T_SEQ + t] = o;
      }
    }
  }
}

// ---------------- output projection: out = Ob @ wprojT + b ----------------
__global__ __launch_bounds__(256) void gemm_proj_kernel(
    const bf16* __restrict__ Ob, const bf16* __restrict__ wb,
    const float* __restrict__ bias, float* __restrict__ out)
{
  __shared__ bf16 As[128][72];
  __shared__ bf16 Bs[128][72];
  f32x4 acc[4][4];
  f32x4 z = {0.f, 0.f, 0.f, 0.f};
#pragma unroll
  for (int i = 0; i < 4; ++i)
#pragma unroll
    for (int j = 0; j < 4; ++j) acc[i][j] = z;
  const int m0 = blockIdx.y * 128, n0 = blockIdx.x * 128;
  gemm_tile(Ob, wb, DM, DM, DM, m0, n0, As, Bs, acc, threadIdx.x);

  const int lane = threadIdx.x & 63, wave = threadIdx.x >> 6;
  const int wmv = (wave >> 1) * 64, wnv = (wave & 1) * 64;
  const int g = lane >> 4, lr = lane & 15;
#pragma unroll
  for (int mi = 0; mi < 4; ++mi) {
#pragma unroll
    for (int ni = 0; ni < 4; ++ni) {
      int col = n0 + wnv + ni * 16 + lr;
      float bv = bias[col];
#pragma unroll
      for (int r = 0; r < 4; ++r) {
        int row = m0 + wmv + mi * 16 + g * 4 + r;
        out[(size_t)row * DM + col] = acc[mi][ni][r] + bv;
      }
    }
  }
}

// ---------------- causal flash attention with HoPE bias ----------------
// grid: (qtile=8, bh=128). block: 256 threads, 4 waves; wave owns 32 q-rows.
__global__ __launch_bounds__(256) void attn_kernel(
    const bf16* __restrict__ Q, const bf16* __restrict__ K,
    const bf16* __restrict__ Vt, const float* __restrict__ table,
    bf16* __restrict__ O)
{
  __shared__ bf16 Ks[128][72];
  __shared__ bf16 Vs[64][136];
  __shared__ bf16 Ps[128][136];
  __shared__ float tbl[1024];

  const int tid = threadIdx.x;
  const int lane = tid & 63;
  const int wave = tid >> 6;
  const int wm = wave * 32;
  const int g = lane >> 4;   // 0..3
  const int lr = lane & 15;
  const int qt = blockIdx.x;
  const int q0 = qt * 128;
  const int bh = blockIdx.y;
  const int h = bh & 15;
  const int b = bh >> 4;

  const bf16* Qp = Q + (size_t)bh * (T_SEQ * HD);
  const bf16* Kp = K + (size_t)bh * (T_SEQ * HD);
  const bf16* Vp = Vt + (size_t)bh * (HD * T_SEQ);

  for (int i = tid; i < 1024; i += 256) tbl[i] = table[i * NH + h];

  bf16x8 qf[2][2];
#pragma unroll
  for (int mi = 0; mi < 2; ++mi)
#pragma unroll
    for (int kk = 0; kk < 2; ++kk)
      qf[mi][kk] = *reinterpret_cast<const bf16x8*>(
          &Qp[(size_t)(q0 + wm + mi * 16 + lr) * HD + kk * 32 + g * 8]);

  float mrow[2][4], lrow[2][4];
  f32x4 oacc[2][4];
  f32x4 z = {0.f, 0.f, 0.f, 0.f};
#pragma unroll
  for (int mi = 0; mi < 2; ++mi)
#pragma unroll
    for (int r = 0; r < 4; ++r) { mrow[mi][r] = -INFINITY; lrow[mi][r] = 0.f; }
#pragma unroll
  for (int mi = 0; mi < 2; ++mi)
#pragma unroll
    for (int nd = 0; nd < 4; ++nd) oacc[mi][nd] = z;

  const int srow = tid >> 3, scol = (tid & 7) * 8;
  const int vrow = tid >> 4, vcol = (tid & 15) * 8;

  const int nkt = qt + 1;
  for (int kt = 0; kt < nkt; ++kt) {
#pragma unroll
    for (int i = 0; i < 4; ++i)
      *reinterpret_cast<bf16x8*>(&Ks[srow + 32 * i][scol]) =
          *reinterpret_cast<const bf16x8*>(&Kp[(size_t)(kt * 128 + srow + 32 * i) * HD + scol]);
#pragma unroll
    for (int i = 0; i < 4; ++i)
      *reinterpret_cast<bf16x8*>(&Vs[vrow + 16 * i][vcol]) =
          *reinterpret_cast<const bf16x8*>(&Vp[(size_t)(vrow + 16 * i) * T_SEQ + kt * 128 + vcol]);
    __syncthreads();

    // S = Q K^T
    f32x4 s[2][8];
#pragma unroll
    for (int mi = 0; mi < 2; ++mi)
#pragma unroll
      for (int ni = 0; ni < 8; ++ni) s[mi][ni] = z;
#pragma unroll
    for (int kk = 0; kk < 2; ++kk) {
      bf16x8 kf[8];
#pragma unroll
      for (int ni = 0; ni < 8; ++ni)
        kf[ni] = *reinterpret_cast<const bf16x8*>(&Ks[ni * 16 + lr][kk * 32 + g * 8]);
#pragma unroll
      for (int mi = 0; mi < 2; ++mi)
#pragma unroll
        for (int ni = 0; ni < 8; ++ni)
          s[mi][ni] = mfma16(qf[mi][kk], kf[ni], s[mi][ni]);
    }

    // scale + bias + causal mask + online softmax
#pragma unroll
    for (int mi = 0; mi < 2; ++mi) {
      const int ib = q0 + wm + mi * 16 + g * 4;
      const int jb = kt * 128 + lr;
      float pm[4] = {-INFINITY, -INFINITY, -INFINITY, -INFINITY};
#pragma unroll
      for (int ni = 0; ni < 8; ++ni) {
#pragma unroll
        for (int r = 0; r < 4; ++r) {
          int d = (ib + r) - (jb + ni * 16);
          float v = s[mi][ni][r] * 0.125f;
          v = (d >= 0) ? (v + tbl[d]) : -INFINITY;
          s[mi][ni][r] = v;
          pm[r] = fmaxf(pm[r], v);
        }
      }
#pragma unroll
      for (int r = 0; r < 4; ++r) {
#pragma unroll
        for (int off = 8; off >= 1; off >>= 1)
          pm[r] = fmaxf(pm[r], __shfl_xor(pm[r], off));
        float mnew = fmaxf(mrow[mi][r], pm[r]);
        float corr = __expf(mrow[mi][r] - mnew);
        mrow[mi][r] = mnew;
        float rs = 0.f;
#pragma unroll
        for (int ni = 0; ni < 8; ++ni) {
          float p = __expf(s[mi][ni][r] - mnew);
          s[mi][ni][r] = p;
          rs += p;
        }
#pragma unroll
        for (int off = 8; off >= 1; off >>= 1)
          rs += __shfl_xor(rs, off);
        lrow[mi][r] = lrow[mi][r] * corr + rs;
#pragma unroll
        for (int nd = 0; nd < 4; ++nd) oacc[mi][nd][r] *= corr;
      }
    }

    // P -> LDS (bf16)
#pragma unroll
    for (int mi = 0; mi < 2; ++mi)
#pragma unroll
      for (int ni = 0; ni < 8; ++ni)
#pragma unroll
        for (int r = 0; r < 4; ++r)
          Ps[wm + mi * 16 + g * 4 + r][ni * 16 + lr] = (bf16)s[mi][ni][r];
    __syncthreads();

    // O += P @ V   (Vt rows are output columns)
#pragma unroll
    for (int kk = 0; kk < 4; ++kk) {
      bf16x8 pf[2], vf[4];
#pragma unroll
      for (int mi = 0; mi < 2; ++mi)
        pf[mi] = *reinterpret_cast<const bf16x8*>(&Ps[wm + mi * 16 + lr][kk * 32 + g * 8]);
#pragma unroll
      for (int nd = 0; nd < 4; ++nd)
        vf[nd] = *reinterpret_cast<const bf16x8*>(&Vs[nd * 16 + lr][kk * 32 + g * 8]);
#pragma unroll
      for (int mi = 0; mi < 2; ++mi)
#pragma unroll
        for (int nd = 0; nd < 4; ++nd)
          oacc[mi][nd] = mfma16(pf[mi], vf[nd], oacc[mi][nd]);
    }
    __syncthreads();
  }

  // epilogue: O[b, t, h*64 + d] = oacc / l
#pragma unroll
  for (int mi = 0; mi < 2; ++mi) {
    int trow = q0 + wm + mi * 16 + g * 4;
#pragma unroll
    for (int r = 0; r < 4; ++r) {
      float inv = 1.0f / lrow[mi][r];
#pragma unroll
      for (int nd = 0; nd < 4; ++nd)
        O[((size_t)(b * T_SEQ + trow + r)) * DM + h * HD + nd * 16 + lr] =
            (bf16)(oacc[mi][nd][r] * inv);
    }
  }
}

extern "C" void kernel_launch(void* const* d_in, const int* in_sizes, int n_in,
                              void* d_out, int out_size, void* d_ws, size_t ws_size,
                              hipStream_t stream) {
  const float* x      = (const float*)d_in[0];  // [8,1024,1024]
  const float* w_qkv  = (const float*)d_in[1];  // [3072,1024]
  const float* b_qkv  = (const float*)d_in[2];  // [3072]
  const float* w_proj = (const float*)d_in[3];  // [1024,1024]
  const float* b_proj = (const float*)d_in[4];  // [1024]
  const float* pos_in = (const float*)d_in[5];  // [256,2]
  float* out = (float*)d_out;

  char* ws = (char*)d_ws;
  bf16* xb     = (bf16*)(ws);                         // 16,777,216 B (reused as Ob)
  bf16* wqkvb  = (bf16*)(ws + 16777216);              //  6,291,456 B
  bf16* wprojb = (bf16*)(ws + 23068672);              //  2,097,152 B
  bf16* Qb     = (bf16*)(ws + 25165824);              // 16,777,216 B
  bf16* Kb     = (bf16*)(ws + 41943040);              // 16,777,216 B
  bf16* Vtb    = (bf16*)(ws + 58720256);              // 16,777,216 B
  float* table = (float*)(ws + 75497472);             //     65,536 B
  bf16* Ob = xb;  // attention output reuses xb (dead after gemm_qkv)

  hope_bias_kernel<<<64, 256, 0, stream>>>(pos_in, table);
  cvt_kernel<<<8192, 256, 0, stream>>>(x, xb, 8 * T_SEQ * DM);
  cvt_kernel<<<3072, 256, 0, stream>>>(w_qkv, wqkvb, 3 * DM * DM);
  cvt_kernel<<<1024, 256, 0, stream>>>(w_proj, wprojb, DM * DM);

  gemm_qkv_kernel<<<dim3(24, 64), 256, 0, stream>>>(xb, wqkvb, b_qkv, Qb, Kb, Vtb);
  attn_kernel<<<dim3(8, 128), 256, 0, stream>>>(Qb, Kb, Vtb, table, Ob);
  gemm_proj_kernel<<<dim3(8, 64), 256, 0, stream>>>(Ob, wprojb, b_proj, out);
}